// Round 6
// baseline (80.144 us; speedup 1.0000x reference)
//
#include <hip/hip_runtime.h>

// N=32, C=256, P=256, H=W=7, K=7, PAD=3.
// y[n,p,oh,ow] = Wk[p]*S1[n,oh,ow] + bk[p]*S2[n,oh,ow] + b_adap[p]
//   S1 = channel-summed spatial autocorrelation of x[n] (S1(d)=S1(-d), 25 lags)
//   S2 = clipped-window sums of z, z = channel-sum image of x[n]
//
// SINGLE dispatch, 256 blocks = (n = bid&31, channel-group g = bid>>5).
// Phase A: each block computes partial S1(25)+z(49) for its 32-channel slice
//          -> ws[(n*8+g)*80]  (same math as round-5 K1, absmax 0.125).
// Ticket:  __threadfence + atomicAdd(g_flags[n]); the 8th arriver wins,
//          resets the flag (module __device__ zero-init -> invariant across
//          replays), and runs the combine + full 256-plane epilogue for n.
// No spinning -> no deadlock; output bitwise-deterministic (fixed g order).

#define HW 49

__device__ int g_flags[32];   // zero at module load; winner restores to 0

__global__ __launch_bounds__(1024, 4) void adap_fused(
    const float* __restrict__ x,   // (32,256,7,7)
    const float* __restrict__ Wk,  // (256,)
    const float* __restrict__ bk,  // (256,)
    const float* __restrict__ ba,  // (256,)
    float* __restrict__ y,         // (32,256,7,7)
    float* __restrict__ ws)        // 256*80 floats
{
    const int bid  = blockIdx.x;
    const int n    = bid & 31;     // bid%8==n%8 -> per-sample XCD locality
    const int g    = bid >> 5;
    const int t    = threadIdx.x;
    const int lane = t & 63;
    const int sub  = t >> 6;       // wave 0..15 (wave-uniform)

    __shared__ float lx[32 * HW];  // 6272 B: this block's channel slice
    __shared__ float sm[80];       // winner: combined partials
    __shared__ float rs[HW];
    __shared__ float s1f[HW], s2[HW];
    __shared__ float lw[256], lb[256], la[256];
    __shared__ int   s_win;

    // ---------------- phase A: slice partials ----------------
    const float4* xs = (const float4*)(x + ((size_t)n * 256 + g * 32) * HW);
    if (t < 392) ((float4*)lx)[t] = xs[t];
    __syncthreads();

    const int c = lane & 31;       // both 32-lane halves span channels 0..31
    float v[HW];
    #pragma unroll
    for (int k = 0; k < HW; ++k) v[k] = lx[c * HW + k];

    float* wbase = ws + (size_t)(n * 8 + g) * 80;

    #pragma unroll
    for (int l = 0; l < 25; ++l) {
        const int own = (l < 16) ? l : (l - 16);
        if (sub == own) {
            const int dh = (l < 4) ? 0 : (l - 4) / 7 + 1;
            const int dw = (l < 4) ? l : (l - 4) % 7 - 3;
            float a = 0.f;
            #pragma unroll
            for (int i = 0; i < 7; ++i) {
                if (i + dh < 0 || i + dh > 6) continue;      // compile-time pruned
                #pragma unroll
                for (int j = 0; j < 7; ++j) {
                    if (j + dw < 0 || j + dw > 6) continue;  // compile-time pruned
                    a += v[(i + dh) * 7 + (j + dw)] * v[i * 7 + j];
                }
            }
            #pragma unroll
            for (int off = 1; off <= 16; off <<= 1) a += __shfl_xor(a, off);
            if (lane == 0) wbase[l] = a;
        }
    }
    #pragma unroll
    for (int p = 0; p < 49; ++p) {
        const int own = (p / 3 > 15) ? 15 : (p / 3);
        if (sub == own) {
            float a = v[p];
            #pragma unroll
            for (int off = 1; off <= 16; off <<= 1) a += __shfl_xor(a, off);
            if (lane == 32) wbase[25 + p] = a;   // lanes 32.. hold same sum
        }
    }

    // ---------------- ticket: last block of sample n wins ----------------
    __threadfence();     // each thread flushes its ws stores to device scope
    __syncthreads();     // all fences before the atomic
    if (t == 0) {
        const int old = atomicAdd(&g_flags[n], 1);
        int win = 0;
        if (old == 7) { atomicExch(&g_flags[n], 0); win = 1; }  // restore invariant
        __threadfence();
        s_win = win;
    }
    __syncthreads();
    if (!s_win) return;

    // ---------------- phase B (winner only): combine + epilogue ----------------
    if (t < 74) {
        const float* wb = ws + (size_t)n * 8 * 80 + t;
        float a = 0.f;
        #pragma unroll
        for (int gg = 0; gg < 8; ++gg) a += wb[gg * 80];
        sm[t] = a;
    }
    if (t >= 128 && t < 384) {     // different waves: stage per-plane params
        const int p = t - 128;
        lw[p] = Wk[p]; lb[p] = bk[p]; la[p] = ba[p];
    }
    __syncthreads();

    if (t < HW) {
        int dh = t / 7 - 3, dw = t % 7 - 3;
        if (dh < 0 || (dh == 0 && dw < 0)) { dh = -dh; dw = -dw; }
        s1f[t] = sm[(dh == 0) ? dw : 4 + (dh - 1) * 7 + (dw + 3)];
        const int i = t / 7, ow = t % 7;
        const int j0 = (ow - 3 < 0) ? 0 : ow - 3, j1 = (ow + 3 > 6) ? 6 : ow + 3;
        float r = 0.f;
        for (int j = j0; j <= j1; ++j) r += sm[25 + i * 7 + j];
        rs[t] = r;
    }
    __syncthreads();

    if (t < HW) {
        const int oh = t / 7, ow = t % 7;
        const int i0 = (oh - 3 < 0) ? 0 : oh - 3, i1 = (oh + 3 > 6) ? 6 : oh + 3;
        float s = 0.f;
        for (int i = i0; i <= i1; ++i) s += rs[i * 7 + ow];
        s2[t] = s;
    }
    __syncthreads();

    // full sample epilogue: 256 planes = 3136 float4 over 1024 threads
    float4* yn4 = (float4*)(y + (size_t)n * 256 * HW);
    #pragma unroll
    for (int it = 0; it < 4; ++it) {
        const int i4 = t + it * 1024;
        if (i4 < 3136) {
            float o[4];
            #pragma unroll
            for (int cc = 0; cc < 4; ++cc) {
                const int idx = i4 * 4 + cc;
                const int p = idx / HW, pos = idx - p * HW;
                o[cc] = lw[p] * s1f[pos] + lb[p] * s2[pos] + la[p];
            }
            yn4[i4] = make_float4(o[0], o[1], o[2], o[3]);
        }
    }
}

extern "C" void kernel_launch(void* const* d_in, const int* in_sizes, int n_in,
                              void* d_out, int out_size, void* d_ws, size_t ws_size,
                              hipStream_t stream) {
    const float* x  = (const float*)d_in[0];
    const float* Wk = (const float*)d_in[1];
    const float* bk = (const float*)d_in[2];
    const float* ba = (const float*)d_in[3];
    float* y  = (float*)d_out;
    float* ws = (float*)d_ws;   // 256*80 floats = 80 KB used

    adap_fused<<<256, 1024, 0, stream>>>(x, Wk, bk, ba, y, ws);
}

// Round 7
// 13.163 us; speedup vs baseline: 6.0886x; 6.0886x over previous
//
#include <hip/hip_runtime.h>

// N=32, C=256, P=256, H=W=7, K=7, PAD=3.
// y[n,p,oh,ow] = Wk[p]*S1[n,oh,ow] + bk[p]*S2[n,oh,ow] + b_adap[p]
//   S1 = channel-summed spatial autocorrelation of x[n] (S1(d)=S1(-d), 25 lags)
//   S2 = clipped-window sums of z, z = channel-sum image of x[n]
//
// Two dispatches (round-5 structure; round-6's fence+atomic fusion cost 65µs
// in L2 writebacks — device-scope fences are NOT cheap on multi-XCD CDNA):
//  K1: 256 blocks = (n, 32-channel group g). Partial S1(25)+z(49) -> ws[(n*8+g)*80].
//  K2: 32 blocks = one per sample: combine 8 partials, expand, write all 256 planes.

#define HW 49

__global__ __launch_bounds__(1024, 4) void k1_partials(
    const float* __restrict__ x,   // (32,256,7,7)
    float* __restrict__ ws)        // (32*8, 80)
{
    const int bid = blockIdx.x;
    const int n = bid & 31, g = bid >> 5;   // bid%8==n%8 -> per-sample XCD locality
    const int t = threadIdx.x;
    const int lane = t & 63;
    const int sub = t >> 6;                 // wave index 0..15 (wave-uniform)

    __shared__ float lx[32 * HW];           // 6272 B: this block's channel slice

    // stage slice: 392 float4, fully coalesced, contiguous
    const float4* xs = (const float4*)(x + ((size_t)n * 256 + g * 32) * HW);
    if (t < 392) ((float4*)lx)[t] = xs[t];
    __syncthreads();

    const int c = lane & 31;                // both 32-lane halves span channels 0..31
    float v[HW];
    #pragma unroll
    for (int k = 0; k < HW; ++k) v[k] = lx[c * HW + k];

    float* wbase = ws + (size_t)(n * 8 + g) * 80;

    // --- S1 lags: owner(l) = l<16 ? l : l-16 (wave-uniform, compile-time bodies) ---
    #pragma unroll
    for (int l = 0; l < 25; ++l) {
        const int own = (l < 16) ? l : (l - 16);
        if (sub == own) {
            const int dh = (l < 4) ? 0 : (l - 4) / 7 + 1;
            const int dw = (l < 4) ? l : (l - 4) % 7 - 3;
            float a = 0.f;
            #pragma unroll
            for (int i = 0; i < 7; ++i) {
                if (i + dh < 0 || i + dh > 6) continue;      // compile-time pruned
                #pragma unroll
                for (int j = 0; j < 7; ++j) {
                    if (j + dw < 0 || j + dw > 6) continue;  // compile-time pruned
                    a += v[(i + dh) * 7 + (j + dw)] * v[i * 7 + j];
                }
            }
            #pragma unroll
            for (int off = 1; off <= 16; off <<= 1) a += __shfl_xor(a, off);
            if (lane == 0) wbase[l] = a;    // sum over channels 0..31 of this slice
        }
    }

    // --- z positions: owner(p) = min(p/3, 15) ---
    #pragma unroll
    for (int p = 0; p < 49; ++p) {
        const int own = (p / 3 > 15) ? 15 : (p / 3);
        if (sub == own) {
            float a = v[p];
            #pragma unroll
            for (int off = 1; off <= 16; off <<= 1) a += __shfl_xor(a, off);
            if (lane == 32) wbase[25 + p] = a;  // lanes 32.. hold identical sum
        }
    }
}

__global__ __launch_bounds__(1024) void k2_epilogue(
    const float* __restrict__ ws,
    const float* __restrict__ Wk,
    const float* __restrict__ bk,
    const float* __restrict__ ba,
    float* __restrict__ y)         // (32,256,7,7)
{
    const int n = blockIdx.x;      // one block per sample
    const int t = threadIdx.x;

    __shared__ float sm[80];       // [0..24]=S1 lags, [25..73]=z
    __shared__ float rs[HW];       // row-window sums of z
    __shared__ float s1f[HW], s2[HW];
    __shared__ float lw[256], lb[256], la[256];

    if (t < 74) {
        const float* wb = ws + (size_t)n * 8 * 80 + t;
        float a = 0.f;
        #pragma unroll
        for (int g = 0; g < 8; ++g) a += wb[g * 80];
        sm[t] = a;
    }
    if (t >= 512 && t < 768) {     // separate waves stage the per-plane params
        const int p = t - 512;
        lw[p] = Wk[p]; lb[p] = bk[p]; la[p] = ba[p];
    }
    __syncthreads();

    if (t < HW) {
        // expand S1 by symmetry
        int dh = t / 7 - 3, dw = t % 7 - 3;
        if (dh < 0 || (dh == 0 && dw < 0)) { dh = -dh; dw = -dw; }
        s1f[t] = sm[(dh == 0) ? dw : 4 + (dh - 1) * 7 + (dw + 3)];
        // separable S2, pass 1: row windows. t = i*7 + ow
        const int i = t / 7, ow = t % 7;
        const int j0 = (ow - 3 < 0) ? 0 : ow - 3, j1 = (ow + 3 > 6) ? 6 : ow + 3;
        float r = 0.f;
        for (int j = j0; j <= j1; ++j) r += sm[25 + i * 7 + j];
        rs[t] = r;
    }
    __syncthreads();

    if (t < HW) {
        // separable S2, pass 2: column windows of rs
        const int oh = t / 7, ow = t % 7;
        const int i0 = (oh - 3 < 0) ? 0 : oh - 3, i1 = (oh + 3 > 6) ? 6 : oh + 3;
        float s = 0.f;
        for (int i = i0; i <= i1; ++i) s += rs[i * 7 + ow];
        s2[t] = s;
    }
    __syncthreads();

    // epilogue: 256 planes = 3136 float4 over 1024 threads, coalesced
    float4* yn4 = (float4*)(y + (size_t)n * 256 * HW);
    #pragma unroll
    for (int it = 0; it < 4; ++it) {
        const int i4 = t + it * 1024;
        if (i4 < 3136) {
            float o[4];
            #pragma unroll
            for (int cc = 0; cc < 4; ++cc) {
                const int idx = i4 * 4 + cc;
                const int p = idx / HW, pos = idx - p * HW;
                o[cc] = lw[p] * s1f[pos] + lb[p] * s2[pos] + la[p];
            }
            yn4[i4] = make_float4(o[0], o[1], o[2], o[3]);
        }
    }
}

extern "C" void kernel_launch(void* const* d_in, const int* in_sizes, int n_in,
                              void* d_out, int out_size, void* d_ws, size_t ws_size,
                              hipStream_t stream) {
    const float* x  = (const float*)d_in[0];
    const float* Wk = (const float*)d_in[1];
    const float* bk = (const float*)d_in[2];
    const float* ba = (const float*)d_in[3];
    float* y  = (float*)d_out;
    float* ws = (float*)d_ws;   // 256*80 floats = 80 KB used

    k1_partials<<<256, 1024, 0, stream>>>(x, ws);
    k2_epilogue<<<32, 1024, 0, stream>>>(ws, Wk, bk, ba, y);
}

// Round 8
// 12.351 us; speedup vs baseline: 6.4887x; 1.0657x over previous
//
#include <hip/hip_runtime.h>

// N=32, C=256, P=256, H=W=7, K=7, PAD=3.
// y[n,p,oh,ow] = Wk[p]*S1[n,oh,ow] + bk[p]*S2[n,oh,ow] + b_adap[p]
//   S1 = channel-summed spatial autocorrelation of x[n] (S1(d)=S1(-d), 25 lags)
//   S2 = clipped-window sums of z, z = channel-sum image of x[n]
//
// Round-5 structure (best measured: 12.05 µs). Two dispatches:
//  K1: 256 blocks = (n, 32-channel group g). Partial S1(25)+z(49) -> ws[(n*8+g)*80].
//      Each block reads only its contiguous 6.1KB slice; no redundant compute.
//  K2: 256 blocks = (n, plane group pg). Combine 8 partials, expand, write y slice.
// (Round 6 showed fence+atomic single-dispatch fusion costs ~65µs in L2
//  writebacks on multi-XCD CDNA; round 7 showed a 32-block epilogue is ~1µs
//  slower than this 256-block one.)

#define HW 49

__global__ __launch_bounds__(1024, 4) void k1_partials(
    const float* __restrict__ x,   // (32,256,7,7)
    float* __restrict__ ws)        // (32*8, 80)
{
    const int bid = blockIdx.x;
    const int n = bid & 31, g = bid >> 5;   // bid%8==n%8 -> per-sample XCD locality
    const int t = threadIdx.x;
    const int lane = t & 63;
    const int sub = t >> 6;                 // wave index 0..15 (wave-uniform)

    __shared__ float lx[32 * HW];           // 6272 B: this block's channel slice

    // stage slice: 392 float4, fully coalesced, contiguous
    const float4* xs = (const float4*)(x + ((size_t)n * 256 + g * 32) * HW);
    if (t < 392) ((float4*)lx)[t] = xs[t];
    __syncthreads();

    const int c = lane & 31;                // both 32-lane halves span channels 0..31
    float v[HW];
    #pragma unroll
    for (int k = 0; k < HW; ++k) v[k] = lx[c * HW + k];

    float* wbase = ws + (size_t)(n * 8 + g) * 80;

    // --- S1 lags: owner(l) = l<16 ? l : l-16 (wave-uniform, compile-time bodies) ---
    #pragma unroll
    for (int l = 0; l < 25; ++l) {
        const int own = (l < 16) ? l : (l - 16);
        if (sub == own) {
            const int dh = (l < 4) ? 0 : (l - 4) / 7 + 1;
            const int dw = (l < 4) ? l : (l - 4) % 7 - 3;
            float a = 0.f;
            #pragma unroll
            for (int i = 0; i < 7; ++i) {
                if (i + dh < 0 || i + dh > 6) continue;      // compile-time pruned
                #pragma unroll
                for (int j = 0; j < 7; ++j) {
                    if (j + dw < 0 || j + dw > 6) continue;  // compile-time pruned
                    a += v[(i + dh) * 7 + (j + dw)] * v[i * 7 + j];
                }
            }
            #pragma unroll
            for (int off = 1; off <= 16; off <<= 1) a += __shfl_xor(a, off);
            if (lane == 0) wbase[l] = a;    // sum over channels 0..31 of this slice
        }
    }

    // --- z positions: owner(p) = min(p/3, 15) ---
    #pragma unroll
    for (int p = 0; p < 49; ++p) {
        const int own = (p / 3 > 15) ? 15 : (p / 3);
        if (sub == own) {
            float a = v[p];
            #pragma unroll
            for (int off = 1; off <= 16; off <<= 1) a += __shfl_xor(a, off);
            if (lane == 32) wbase[25 + p] = a;  // lanes 32.. hold identical sum
        }
    }
}

__global__ __launch_bounds__(512) void k2_epilogue(
    const float* __restrict__ ws,
    const float* __restrict__ Wk,
    const float* __restrict__ bk,
    const float* __restrict__ ba,
    float* __restrict__ y)         // (32,256,7,7)
{
    const int bid = blockIdx.x;
    const int n = bid & 31, pg = bid >> 5;
    const int t = threadIdx.x;

    __shared__ float sm[80];       // [0..24]=S1 lags, [25..73]=z
    __shared__ float rs[HW];       // row-window sums of z
    __shared__ float s1f[HW], s2[HW];
    __shared__ float lwk[32], lbk[32], lba[32];

    if (t < 32) { const int p = pg * 32 + t; lwk[t] = Wk[p]; lbk[t] = bk[p]; lba[t] = ba[p]; }
    if (t < 74) {
        const float* wb = ws + (size_t)n * 8 * 80 + t;
        float a = 0.f;
        #pragma unroll
        for (int g = 0; g < 8; ++g) a += wb[g * 80];
        sm[t] = a;
    }
    __syncthreads();

    if (t < HW) {
        // expand S1 by symmetry
        int dh = t / 7 - 3, dw = t % 7 - 3;
        if (dh < 0 || (dh == 0 && dw < 0)) { dh = -dh; dw = -dw; }
        s1f[t] = sm[(dh == 0) ? dw : 4 + (dh - 1) * 7 + (dw + 3)];
        // separable S2, pass 1: row windows. t = i*7 + ow
        const int i = t / 7, ow = t % 7;
        const int j0 = (ow - 3 < 0) ? 0 : ow - 3, j1 = (ow + 3 > 6) ? 6 : ow + 3;
        float r = 0.f;
        for (int j = j0; j <= j1; ++j) r += sm[25 + i * 7 + j];
        rs[t] = r;
    }
    __syncthreads();

    if (t < HW) {
        // separable S2, pass 2: column windows of rs
        const int oh = t / 7, ow = t % 7;
        const int i0 = (oh - 3 < 0) ? 0 : oh - 3, i1 = (oh + 3 > 6) ? 6 : oh + 3;
        float s = 0.f;
        for (int i = i0; i <= i1; ++i) s += rs[i * 7 + ow];
        s2[t] = s;
    }
    __syncthreads();

    // epilogue: 32 planes = 392 float4, coalesced
    float4* yn4 = (float4*)(y + ((size_t)n * 256 + pg * 32) * HW);
    if (t < 392) {
        float o[4];
        #pragma unroll
        for (int cc = 0; cc < 4; ++cc) {
            const int idx = t * 4 + cc;
            const int p = idx / HW, pos = idx - p * HW;
            o[cc] = lwk[p] * s1f[pos] + lbk[p] * s2[pos] + lba[p];
        }
        yn4[t] = make_float4(o[0], o[1], o[2], o[3]);
    }
}

extern "C" void kernel_launch(void* const* d_in, const int* in_sizes, int n_in,
                              void* d_out, int out_size, void* d_ws, size_t ws_size,
                              hipStream_t stream) {
    const float* x  = (const float*)d_in[0];
    const float* Wk = (const float*)d_in[1];
    const float* bk = (const float*)d_in[2];
    const float* ba = (const float*)d_in[3];
    float* y  = (float*)d_out;
    float* ws = (float*)d_ws;   // 256*80 floats = 80 KB used

    k1_partials<<<256, 1024, 0, stream>>>(x, ws);
    k2_epilogue<<<256, 512, 0, stream>>>(ws, Wk, bk, ba, y);
}